// Round 4
// baseline (7686.225 us; speedup 1.0000x reference)
//
#include <hip/hip_runtime.h>
#include <hip/hip_bf16.h>

typedef __hip_bfloat16 bf16;

#define B   4
#define N   16384
#define D   192
#define H_  6
#define DH  32
#define MCL 64
#define KC  256
#define DFF 768
#define GW  128
#define MTOK (B * N)   // 65536 tokens
#define CHUNK 16384    // tokens per MLP/qkv chunk (= one batch)

__device__ __forceinline__ float b2f(bf16 x) { return __bfloat162float(x); }
__device__ __forceinline__ bf16  f2b(float x) { return __float2bfloat16(x); }

// ---- fallback: zero output (signals ws_size too small via absmax==max|ref|~5.69) ----
__global__ void zero_out_kernel(float* __restrict__ out, size_t n) {
    size_t i = blockIdx.x * (size_t)blockDim.x + threadIdx.x;
    if (i < n) out[i] = 0.f;
}

// ---- order_idx: keys are a bijection onto 0..n-1 -> direct scatter, no argsort ----
__global__ void build_idx(const float* __restrict__ pos, int* __restrict__ order) {
    int tid = blockIdx.x * blockDim.x + threadIdx.x;
    if (tid >= B * N) return;
    int b = tid / N;
    float px = pos[(size_t)tid * 2 + 0];
    float py = pos[(size_t)tid * 2 + 1];
    int ix = (int)floorf(px);
    int iy = (int)floorf(py);
    int key = iy * GW + ((iy & 1) ? (GW - 1 - ix) : ix);
    key = (int)(((unsigned)key) & (N - 1));   // safety mask: never OOB even if pos misread
    order[(size_t)b * N + key] = tid % N;
}

// ---- LayerNorm: one wave (64 lanes) per token, 3 channels per lane; bf16 out ----
__global__ void ln_kernel(const float* __restrict__ x, const float* __restrict__ g,
                          const float* __restrict__ bb, bf16* __restrict__ out) {
    int wave = (blockIdx.x * blockDim.x + threadIdx.x) >> 6;
    int lane = threadIdx.x & 63;
    if (wave >= MTOK) return;
    const float* xr = x + (size_t)wave * D;
    float v0 = xr[lane], v1 = xr[lane + 64], v2 = xr[lane + 128];
    float s  = v0 + v1 + v2;
    float ss = v0 * v0 + v1 * v1 + v2 * v2;
    #pragma unroll
    for (int off = 32; off; off >>= 1) {
        s  += __shfl_xor(s, off);
        ss += __shfl_xor(ss, off);
    }
    float mean = s * (1.0f / D);
    float var  = ss * (1.0f / D) - mean * mean;
    float rs   = rsqrtf(var + 1e-5f);
    bf16* o = out + (size_t)wave * D;
    o[lane]       = f2b((v0 - mean) * rs * g[lane]       + bb[lane]);
    o[lane + 64]  = f2b((v1 - mean) * rs * g[lane + 64]  + bb[lane + 64]);
    o[lane + 128] = f2b((v2 - mean) * rs * g[lane + 128] + bb[lane + 128]);
}

// ---- LDS-tiled GEMM: A bf16 (activations), B/bias fp32 (weights), fp32 accumulate ----
template<bool GELU, bool RESID>
__global__ void gemm_kernel(const bf16* __restrict__ A, const float* __restrict__ Bw,
                            const float* __restrict__ bias, bf16* __restrict__ Cout,
                            float* __restrict__ Cres, int M, int Nn, int K) {
    __shared__ float As[16][17];
    __shared__ float Bs[16][17];
    int tx = threadIdx.x, ty = threadIdx.y;
    int row = blockIdx.y * 16 + ty;
    int col = blockIdx.x * 16 + tx;
    float acc = 0.f;
    for (int k0 = 0; k0 < K; k0 += 16) {
        As[ty][tx] = b2f(A[(size_t)row * K + k0 + tx]);
        Bs[ty][tx] = Bw[(size_t)(k0 + ty) * Nn + col];
        __syncthreads();
        #pragma unroll
        for (int kk = 0; kk < 16; kk++) acc += As[ty][kk] * Bs[kk][tx];
        __syncthreads();
    }
    acc += bias[col];
    if (GELU) {
        float x3 = acc * acc * acc;
        acc = 0.5f * acc * (1.f + tanhf(0.7978845608028654f * (acc + 0.044715f * x3)));
    }
    size_t idx = (size_t)row * Nn + col;
    if (RESID) Cres[idx] += acc;
    else       Cout[idx] = f2b(acc);
}

// ---- cluster attention for ONE batch: one wave per (head, cluster) ----
__global__ void attn_kernel(const bf16* __restrict__ qkv_b, const int* __restrict__ order_b,
                            bf16* __restrict__ out_b) {
    __shared__ float ks[MCL][DH + 1];
    __shared__ float vs[MCL][DH + 1];
    int h = blockIdx.x, c = blockIdx.y;
    int lane = threadIdx.x;  // 0..63: this lane's query row (rank within cluster)
    int t = (int)(((unsigned)order_b[c * MCL + lane]) & (N - 1));  // safety mask
    const bf16* base = qkv_b + (size_t)t * (3 * D) + h * DH;
    const float scale = 0.17677669529663687f;  // 32^-0.5
    float qr[DH];
    #pragma unroll
    for (int d = 0; d < DH; d++) {
        qr[d]       = b2f(base[d]) * scale;    // fold scale into q
        ks[lane][d] = b2f(base[D + d]);
        vs[lane][d] = b2f(base[2 * D + d]);
    }
    __syncthreads();
    float mx = -1e30f;
    for (int p = 0; p < MCL; p++) {
        float dot = 0.f;
        #pragma unroll
        for (int d = 0; d < DH; d++) dot += qr[d] * ks[p][d];
        mx = fmaxf(mx, dot);
    }
    float sum = 0.f;
    float ov[DH];
    #pragma unroll
    for (int d = 0; d < DH; d++) ov[d] = 0.f;
    for (int p = 0; p < MCL; p++) {
        float dot = 0.f;
        #pragma unroll
        for (int d = 0; d < DH; d++) dot += qr[d] * ks[p][d];
        float e = __expf(dot - mx);
        sum += e;
        #pragma unroll
        for (int d = 0; d < DH; d++) ov[d] += e * vs[p][d];
    }
    float inv = 1.f / sum;
    bf16* op = out_b + (size_t)t * D + h * DH;  // scatter back to token order
    #pragma unroll
    for (int d = 0; d < DH; d++) op[d] = f2b(ov[d] * inv);
}

extern "C" void kernel_launch(void* const* d_in, const int* in_sizes, int n_in,
                              void* d_out, int out_size, void* d_ws, size_t ws_size,
                              hipStream_t stream) {
    const float* x_in   = (const float*)d_in[0];
    const float* pos    = (const float*)d_in[1];
    const float* ln1_g  = (const float*)d_in[2];
    const float* ln1_b  = (const float*)d_in[3];
    const float* w_qkv  = (const float*)d_in[4];
    const float* b_qkv  = (const float*)d_in[5];
    const float* w_proj = (const float*)d_in[6];
    const float* b_proj = (const float*)d_in[7];
    const float* ln2_g  = (const float*)d_in[8];
    const float* ln2_b  = (const float*)d_in[9];
    const float* w_fc1  = (const float*)d_in[10];
    const float* b_fc1  = (const float*)d_in[11];
    const float* w_fc2  = (const float*)d_in[12];
    const float* b_fc2  = (const float*)d_in[13];

    // ---- workspace layout (~101 MiB) ----
    size_t sz_x     = (size_t)MTOK * D * 4;      // 50.3 MB  fp32 residual stream
    size_t sz_xnob  = (size_t)MTOK * D * 2;      // 25.2 MB  LN out / attn out (bf16, overlaid)
    size_t sz_cbuf  = (size_t)CHUNK * DFF * 2;   // 25.2 MB  per-chunk qkv(576)/hidden(768) bf16
    size_t sz_order = (size_t)B * N * 4;         //  0.26 MB
    size_t need = sz_x + sz_xnob + sz_cbuf + sz_order;
    if (ws_size < need) {
        zero_out_kernel<<<(out_size + 255) / 256, 256, 0, stream>>>((float*)d_out, (size_t)out_size);
        return;
    }
    char* ws = (char*)d_ws;
    float* x_f32 = (float*)ws;  ws += sz_x;
    bf16*  xnob  = (bf16*)ws;   ws += sz_xnob;
    bf16*  cbuf  = (bf16*)ws;   ws += sz_cbuf;
    int*   order = (int*)ws;    ws += sz_order;

    build_idx<<<(B * N + 255) / 256, 256, 0, stream>>>(pos, order);

    size_t total = (size_t)MTOK * D;
    hipMemcpyAsync(x_f32, x_in, total * sizeof(float), hipMemcpyDeviceToDevice, stream);

    for (int layer = 0; layer < 2; layer++) {
        // --- attention block ---
        ln_kernel<<<MTOK / 4, 256, 0, stream>>>(x_f32, ln1_g + layer * D, ln1_b + layer * D, xnob);
        for (int b = 0; b < B; b++) {
            gemm_kernel<false, false><<<dim3(3 * D / 16, N / 16), dim3(16, 16), 0, stream>>>(
                xnob + (size_t)b * N * D, w_qkv + (size_t)layer * D * 3 * D,
                b_qkv + layer * 3 * D, cbuf, nullptr, N, 3 * D, D);
            attn_kernel<<<dim3(H_, KC), 64, 0, stream>>>(
                cbuf, order + (size_t)b * N, xnob + (size_t)b * N * D);
        }
        gemm_kernel<false, true><<<dim3(D / 16, MTOK / 16), dim3(16, 16), 0, stream>>>(
            xnob, w_proj + (size_t)layer * D * D, b_proj + layer * D, nullptr, x_f32,
            MTOK, D, D);
        // --- MLP block ---
        ln_kernel<<<MTOK / 4, 256, 0, stream>>>(x_f32, ln2_g + layer * D, ln2_b + layer * D, xnob);
        for (int c = 0; c < MTOK / CHUNK; c++) {
            gemm_kernel<true, false><<<dim3(DFF / 16, CHUNK / 16), dim3(16, 16), 0, stream>>>(
                xnob + (size_t)c * CHUNK * D, w_fc1 + (size_t)layer * D * DFF,
                b_fc1 + layer * DFF, cbuf, nullptr, CHUNK, DFF, D);
            gemm_kernel<false, true><<<dim3(D / 16, CHUNK / 16), dim3(16, 16), 0, stream>>>(
                cbuf, w_fc2 + (size_t)layer * DFF * D, b_fc2 + layer * D, nullptr,
                x_f32 + (size_t)c * CHUNK * D, CHUNK, D, DFF);
        }
    }
    // Output dtype = reference output dtype = float32.
    hipMemcpyAsync(d_out, x_f32, total * sizeof(float), hipMemcpyDeviceToDevice, stream);
}

// Round 5
// 1144.488 us; speedup vs baseline: 6.7159x; 6.7159x over previous
//
#include <hip/hip_runtime.h>
#include <hip/hip_bf16.h>

typedef __hip_bfloat16 bf16;
typedef __attribute__((ext_vector_type(8))) short short8;
typedef __attribute__((ext_vector_type(4))) float f32x4;

#define B_   4
#define N_   16384
#define D_   192
#define H6   6
#define DH   32
#define MCL  64
#define KC   256
#define DFF  768
#define GW   128
#define MTOK (B_ * N_)    // 65536 tokens
#define MLPC 8192         // MLP chunk rows

__device__ __forceinline__ float b2f(bf16 x) { return __bfloat162float(x); }
__device__ __forceinline__ bf16  f2b(float x) { return __float2bfloat16(x); }
__device__ __forceinline__ float bfbits2f(short u) {
    union { unsigned u; float f; } x; x.u = ((unsigned)(unsigned short)u) << 16; return x.f;
}
__device__ __forceinline__ short f2bbits(float x) {
    bf16 h = __float2bfloat16(x); return *(short*)&h;
}

// ---- fallback: zero output ----
__global__ void zero_out_kernel(float* __restrict__ out, size_t n) {
    size_t i = blockIdx.x * (size_t)blockDim.x + threadIdx.x;
    if (i < n) out[i] = 0.f;
}

// ---- order: scanline keys are a bijection onto 0..n-1 -> direct scatter ----
__global__ void build_idx(const float* __restrict__ pos, int* __restrict__ order) {
    int tid = blockIdx.x * blockDim.x + threadIdx.x;
    if (tid >= B_ * N_) return;
    int b = tid / N_;
    int ix = (int)floorf(pos[(size_t)tid * 2 + 0]);
    int iy = (int)floorf(pos[(size_t)tid * 2 + 1]);
    int key = iy * GW + ((iy & 1) ? (GW - 1 - ix) : ix);
    key = (int)(((unsigned)key) & (N_ - 1));
    order[(size_t)b * N_ + key] = tid % N_;
}

// ---- weight prep: fp32 row-major [K][N] -> bf16 MFMA-B-fragment order ----
// chunk(ntile,kt) of 512 elems contiguous; within: ((k%32)/8*16 + n%16)*8 + k%8
__global__ void wprep(const float* __restrict__ w, bf16* __restrict__ out, int K, int Nn) {
    int tid = blockIdx.x * blockDim.x + threadIdx.x;
    if (tid >= K * Nn) return;
    int k = tid / Nn, n = tid % Nn;
    int idx = ((n >> 4) * (K >> 5) + (k >> 5)) * 512 + (((k >> 3) & 3) * 16 + (n & 15)) * 8 + (k & 7);
    out[idx] = f2b(w[tid]);
}

// ---- LayerNorm: one wave per token ----
__global__ void ln_kernel(const float* __restrict__ x, const float* __restrict__ g,
                          const float* __restrict__ bb, bf16* __restrict__ out) {
    int wave = (blockIdx.x * blockDim.x + threadIdx.x) >> 6;
    int lane = threadIdx.x & 63;
    if (wave >= MTOK) return;
    const float* xr = x + (size_t)wave * D_;
    float v0 = xr[lane], v1 = xr[lane + 64], v2 = xr[lane + 128];
    float s  = v0 + v1 + v2;
    float ss = v0 * v0 + v1 * v1 + v2 * v2;
    #pragma unroll
    for (int off = 32; off; off >>= 1) {
        s  += __shfl_xor(s, off);
        ss += __shfl_xor(ss, off);
    }
    float mean = s * (1.0f / D_);
    float var  = ss * (1.0f / D_) - mean * mean;
    float rs   = rsqrtf(var + 1e-5f);
    bf16* o = out + (size_t)wave * D_;
    o[lane]       = f2b((v0 - mean) * rs * g[lane]       + bb[lane]);
    o[lane + 64]  = f2b((v1 - mean) * rs * g[lane + 64]  + bb[lane + 64]);
    o[lane + 128] = f2b((v2 - mean) * rs * g[lane + 128] + bb[lane + 128]);
}

// ---- MFMA GEMM: C[M,N] = A[M,K] @ W[K,N] (+bias, opt GELU, opt fp32 residual add)
// A bf16 row-major; Wf bf16 fragment-order; 128x64 tile, BK=32, 4 waves.
template<bool GELU, bool RESID>
__global__ __launch_bounds__(256) void mfma_gemm(
    const bf16* __restrict__ A, const bf16* __restrict__ Wf,
    const float* __restrict__ bias, bf16* __restrict__ Cout,
    float* __restrict__ Cres, int M, int Nn, int K) {
    __shared__ short Asl[128 * 32];  // frag order: mtile*512 + (quad*16+row16)*8 + j
    __shared__ short Bsl[64 * 32];   // ntile*512 + (quadk*16+col16)*8 + j
    int tid = threadIdx.x;
    int bm = blockIdx.x, bn = blockIdx.y;
    int w = tid >> 6, lane = tid & 63;
    int wm = w >> 1, wn = w & 1;
    int quad = lane >> 4, l16 = lane & 15;
    int kt_num = K >> 5;

    int ar = tid >> 2;       // A-staging: row (0..63, +64), quad = tid&3
    int aq = tid & 3;
    int bnt = tid >> 6;      // B-staging: ntile chunk 0..3
    int boff = (tid & 63) * 8;

    f32x4 acc[4][2] = {};
    for (int kt = 0; kt < kt_num; ++kt) {
        const bf16* Ag = A + (size_t)(bm * 128) * K + kt * 32;
        short8 va0 = *(const short8*)(Ag + (size_t)ar * K + aq * 8);
        short8 va1 = *(const short8*)(Ag + (size_t)(ar + 64) * K + aq * 8);
        short8 vb  = *(const short8*)(Wf + ((size_t)(bn * 4 + bnt) * kt_num + kt) * 512 + boff);
        *(short8*)&Asl[(ar >> 4) * 512 + (aq * 16 + (ar & 15)) * 8] = va0;
        *(short8*)&Asl[((ar >> 4) + 4) * 512 + (aq * 16 + (ar & 15)) * 8] = va1;
        *(short8*)&Bsl[bnt * 512 + boff] = vb;
        __syncthreads();
        short8 af[4], bfr[2];
        #pragma unroll
        for (int mt = 0; mt < 4; ++mt)
            af[mt] = *(short8*)&Asl[(wm * 4 + mt) * 512 + lane * 8];
        #pragma unroll
        for (int nt = 0; nt < 2; ++nt)
            bfr[nt] = *(short8*)&Bsl[(wn * 2 + nt) * 512 + lane * 8];
        #pragma unroll
        for (int mt = 0; mt < 4; ++mt)
            #pragma unroll
            for (int nt = 0; nt < 2; ++nt)
                acc[mt][nt] = __builtin_amdgcn_mfma_f32_16x16x32_bf16(af[mt], bfr[nt], acc[mt][nt], 0, 0, 0);
        __syncthreads();
    }
    #pragma unroll
    for (int mt = 0; mt < 4; ++mt) {
        int row_base = bm * 128 + wm * 64 + mt * 16 + quad * 4;
        #pragma unroll
        for (int nt = 0; nt < 2; ++nt) {
            int col = bn * 64 + wn * 32 + nt * 16 + l16;
            float bv = bias[col];
            #pragma unroll
            for (int r = 0; r < 4; ++r) {
                float v = acc[mt][nt][r] + bv;
                if (GELU) {
                    float inner = 0.7978845608028654f * (v + 0.044715f * v * v * v);
                    inner = fminf(fmaxf(inner, -12.f), 12.f);
                    float e = __expf(2.f * inner);
                    v = 0.5f * v * (1.f + (e - 1.f) / (e + 1.f));
                }
                size_t idx = (size_t)(row_base + r) * Nn + col;
                if (RESID) Cres[idx] += v; else Cout[idx] = f2b(v);
            }
        }
    }
}

// ---- cluster attention, one wave per (head, cluster); single-pass online softmax ----
__global__ void attn_kernel(const bf16* __restrict__ qkv_b, const int* __restrict__ order_b,
                            bf16* __restrict__ out_b) {
    __shared__ float ks[MCL][36];
    __shared__ float vs[MCL][36];
    int h = blockIdx.x, c = blockIdx.y;
    int lane = threadIdx.x;
    int t = (int)(((unsigned)order_b[c * MCL + lane]) & (N_ - 1));
    const short* base = (const short*)(qkv_b + (size_t)t * (3 * D_) + h * DH);
    const float scale = 0.17677669529663687f;
    float qf[DH];
    #pragma unroll
    for (int j = 0; j < 4; ++j) {
        short8 sq = *(const short8*)(base + j * 8);
        short8 sk = *(const short8*)(base + D_ + j * 8);
        short8 sv = *(const short8*)(base + 2 * D_ + j * 8);
        f32x4 k0, k1, v0, v1;
        #pragma unroll
        for (int e = 0; e < 8; ++e) qf[j * 8 + e] = bfbits2f(sq[e]) * scale;
        #pragma unroll
        for (int e = 0; e < 4; ++e) { k0[e] = bfbits2f(sk[e]); k1[e] = bfbits2f(sk[e + 4]); }
        #pragma unroll
        for (int e = 0; e < 4; ++e) { v0[e] = bfbits2f(sv[e]); v1[e] = bfbits2f(sv[e + 4]); }
        *(f32x4*)&ks[lane][j * 8]     = k0;
        *(f32x4*)&ks[lane][j * 8 + 4] = k1;
        *(f32x4*)&vs[lane][j * 8]     = v0;
        *(f32x4*)&vs[lane][j * 8 + 4] = v1;
    }
    __syncthreads();
    float mx = -1e30f, sum = 0.f;
    float ov[DH];
    #pragma unroll
    for (int d = 0; d < DH; ++d) ov[d] = 0.f;
    for (int p = 0; p < MCL; ++p) {
        float dot = 0.f;
        #pragma unroll
        for (int d = 0; d < DH; ++d) dot += qf[d] * ks[p][d];
        float nm = fmaxf(mx, dot);
        float corr = __expf(mx - nm);   // 1 if no new max; 0 on first iter
        float e = __expf(dot - nm);
        sum = sum * corr + e;
        #pragma unroll
        for (int d = 0; d < DH; ++d) ov[d] = ov[d] * corr + e * vs[p][d];
        mx = nm;
    }
    float inv = 1.f / sum;
    short* op = (short*)(out_b + (size_t)t * D_ + h * DH);
    #pragma unroll
    for (int j = 0; j < 4; ++j) {
        short8 o;
        #pragma unroll
        for (int e = 0; e < 8; ++e) o[e] = f2bbits(ov[j * 8 + e] * inv);
        *(short8*)(op + j * 8) = o;
    }
}

extern "C" void kernel_launch(void* const* d_in, const int* in_sizes, int n_in,
                              void* d_out, int out_size, void* d_ws, size_t ws_size,
                              hipStream_t stream) {
    const float* x_in   = (const float*)d_in[0];
    const float* pos    = (const float*)d_in[1];
    const float* ln1_g  = (const float*)d_in[2];
    const float* ln1_b  = (const float*)d_in[3];
    const float* w_qkv  = (const float*)d_in[4];
    const float* b_qkv  = (const float*)d_in[5];
    const float* w_proj = (const float*)d_in[6];
    const float* b_proj = (const float*)d_in[7];
    const float* ln2_g  = (const float*)d_in[8];
    const float* ln2_b  = (const float*)d_in[9];
    const float* w_fc1  = (const float*)d_in[10];
    const float* b_fc1  = (const float*)d_in[11];
    const float* w_fc2  = (const float*)d_in[12];
    const float* b_fc2  = (const float*)d_in[13];

    // ---- workspace (~92 MiB; round-4 proved >=101 MiB available) ----
    size_t sz_x     = (size_t)MTOK * D_ * 4;       // 50.3 MB fp32 residual
    size_t sz_xnob  = (size_t)MTOK * D_ * 2;       // 25.2 MB LN out / attn out bf16
    size_t sz_cbuf  = (size_t)N_ * 3 * D_ * 2;     // 18.9 MB qkv-per-batch / MLP hidden
    size_t sz_order = (size_t)B_ * N_ * 4;         //  0.26 MB
    size_t sz_wbuf  = (size_t)2 * 442368 * 2;      //  1.73 MB frag-order weights
    size_t need = sz_x + sz_xnob + sz_cbuf + sz_order + sz_wbuf;
    if (ws_size < need) {
        zero_out_kernel<<<(out_size + 255) / 256, 256, 0, stream>>>((float*)d_out, (size_t)out_size);
        return;
    }
    char* ws = (char*)d_ws;
    float* x_f32 = (float*)ws;  ws += sz_x;
    bf16*  xnob  = (bf16*)ws;   ws += sz_xnob;
    bf16*  cbuf  = (bf16*)ws;   ws += sz_cbuf;
    int*   order = (int*)ws;    ws += sz_order;
    bf16*  wbuf  = (bf16*)ws;   ws += sz_wbuf;

    // frag-order weight pointers (per layer)
    bf16* wq[2];  bf16* wp[2];  bf16* wf1[2];  bf16* wf2[2];
    for (int l = 0; l < 2; ++l) {
        bf16* p = wbuf + (size_t)l * 442368;
        wq[l] = p;            p += 110592;   // 192x576
        wp[l] = p;            p += 36864;    // 192x192
        wf1[l] = p;           p += 147456;   // 192x768
        wf2[l] = p;                          // 768x192
    }
    for (int l = 0; l < 2; ++l) {
        wprep<<<(192 * 576) / 256, 256, 0, stream>>>(w_qkv + (size_t)l * 192 * 576, wq[l], 192, 576);
        wprep<<<(192 * 192) / 256, 256, 0, stream>>>(w_proj + (size_t)l * 192 * 192, wp[l], 192, 192);
        wprep<<<(192 * 768) / 256, 256, 0, stream>>>(w_fc1 + (size_t)l * 192 * 768, wf1[l], 192, 768);
        wprep<<<(768 * 192) / 256, 256, 0, stream>>>(w_fc2 + (size_t)l * 768 * 192, wf2[l], 768, 192);
    }

    build_idx<<<(B_ * N_ + 255) / 256, 256, 0, stream>>>(pos, order);

    size_t total = (size_t)MTOK * D_;
    hipMemcpyAsync(x_f32, x_in, total * sizeof(float), hipMemcpyDeviceToDevice, stream);

    for (int l = 0; l < 2; ++l) {
        // --- attention block ---
        ln_kernel<<<MTOK / 4, 256, 0, stream>>>(x_f32, ln1_g + l * D_, ln1_b + l * D_, xnob);
        for (int b = 0; b < B_; b++) {
            mfma_gemm<false, false><<<dim3(N_ / 128, 576 / 64), 256, 0, stream>>>(
                xnob + (size_t)b * N_ * D_, wq[l], b_qkv + l * 576, cbuf, nullptr, N_, 576, 192);
            attn_kernel<<<dim3(H6, KC), 64, 0, stream>>>(
                cbuf, order + (size_t)b * N_, xnob + (size_t)b * N_ * D_);
        }
        mfma_gemm<false, true><<<dim3(MTOK / 128, 192 / 64), 256, 0, stream>>>(
            xnob, wp[l], b_proj + l * 192, nullptr, x_f32, MTOK, 192, 192);
        // --- MLP block ---
        ln_kernel<<<MTOK / 4, 256, 0, stream>>>(x_f32, ln2_g + l * D_, ln2_b + l * D_, xnob);
        for (int c = 0; c < MTOK / MLPC; c++) {
            mfma_gemm<true, false><<<dim3(MLPC / 128, 768 / 64), 256, 0, stream>>>(
                xnob + (size_t)c * MLPC * D_, wf1[l], b_fc1 + l * 768, cbuf, nullptr, MLPC, 768, 192);
            mfma_gemm<false, true><<<dim3(MLPC / 128, 192 / 64), 256, 0, stream>>>(
                cbuf, wf2[l], b_fc2 + l * 192, nullptr, x_f32 + (size_t)c * MLPC * D_, MLPC, 192, 768);
        }
    }
    hipMemcpyAsync(d_out, x_f32, total * sizeof(float), hipMemcpyDeviceToDevice, stream);
}